// Round 5
// baseline (366.699 us; speedup 1.0000x reference)
//
#include <hip/hip_runtime.h>
#include <stdint.h>
#include <stddef.h>

typedef short bfrag __attribute__((ext_vector_type(8)));
typedef float f32x4 __attribute__((ext_vector_type(4)));

#define FSTRIDE 576       // feats row stride (560 + 16 zero pad), 18 K-steps for MLP
#define NSEQ 7

__constant__ int c_ks[5] = {1, 3, 5, 7, 9};

// per-ksize active MFMA K-steps (B is exactly zero outside): s in [lo, lo+n)
#define SLO0 3
#define SLO1 2
#define SLO2 1
#define SLO3 0
#define SLO4 0
#define SN0 1
#define SN1 3
#define SN2 5
#define SN3 6
#define SN4 7

static __device__ __forceinline__ unsigned short f2bf(float f) {
  unsigned int u = __float_as_uint(f);
  u += 0x7FFFu + ((u >> 16) & 1u);   // RNE
  return (unsigned short)(u >> 16);
}

// ---------------- prep: pack conv weights + lin1 into B-fragment layout ----------
struct PrepArgs {
  const float* Wk[5];
  const float* lin1_w;
  bfrag* Wpack;
  bfrag* lin1pack;
};

__global__ __launch_bounds__(256) void prep_kernel(PrepArgs a) {
  int tid = blockIdx.x * 256 + threadIdx.x;
  const int NW = NSEQ * 5 * 7 * 64;
  if (tid < NW) {
    int lane = tid & 63, rest = tid >> 6;
    int step = rest % 7, nt = (rest / 7) % 5, seq = rest / 35;
    int quad = lane >> 4, f = lane & 15;
    int ks = c_ks[nt], off = (9 - ks) >> 1;
    const float* W = a.Wk[nt];
    bfrag s;
#pragma unroll
    for (int j = 0; j < 8; ++j) {
      int k = step * 32 + quad * 8 + j;
      int t = k / 24, c = k % 24;
      int tap = t - off;
      float val = 0.f;
      if (c < 20 && tap >= 0 && tap < ks)
        val = W[((seq * 16 + f) * 20 + c) * ks + tap] * 0.2f;  // fold /5
      s[j] = (short)f2bf(val);
    }
    a.Wpack[tid] = s;
  } else if (tid < NW + 4 * 18 * 64) {
    int t2 = tid - NW;
    int lane = t2 & 63, rest = t2 >> 6;
    int step = rest % 18, nt = rest / 18;
    int quad = lane >> 4, col = lane & 15;
    int n = nt * 16 + col;
    bfrag s;
#pragma unroll
    for (int j = 0; j < 8; ++j) {
      int k = step * 32 + quad * 8 + j;
      float val = (k < 560) ? a.lin1_w[n * 560 + k] : 0.f;
      s[j] = (short)f2bf(val);
    }
    a.lin1pack[t2] = s;
  }
}

// ---------------- conv+relu+gmax: one dispatch, per-seq constexpr bodies ----------------
struct ConvArgs {
  const float* x[NSEQ];
  const bfrag* Wpack;
  unsigned short* feats;   // bf16 [B][FSTRIDE]
};

// TBB=16 samples/block, P=41 positions (pos = xi + 4; halo+pad zeroed).
// MTc==1: Lp = 1<<SHIFTc <= 16; tiles of 16 rows; bpt = 16>>SHIFTc samples/tile.
// MTc==2: seq6 (L=18): per sample two OVERLAPPING dense tiles: rows 0-15 and 2-17
//         (rows 2-15 recomputed — idempotent under max; zero masking needed).
template <int Lc, int SHIFTc, int MTc>
__device__ __forceinline__ void conv_body(unsigned short* xl, const ConvArgs& a,
                                          const int seq, const int b0) {
  constexpr int TBB = 16, P = 41;
  const int tid = threadIdx.x;
  const float* xg = a.x[seq];

  // zero staging region (covers c-pad, l-pad, halo)
  for (int i = tid; i < TBB * P * 24 / 2; i += 256) ((unsigned int*)xl)[i] = 0u;
  __syncthreads();
  // stage x -> bf16 [b][pos=xi+4][c]
  for (int r = tid; r < TBB * 20; r += 256) {
    int b = r / 20, c = r % 20;
    const float* src = xg + (size_t)((b0 + b) * 20 + c) * Lc;
    unsigned short* dst = xl + (b * P + 4) * 24 + c;
#pragma unroll
    for (int xi = 0; xi < Lc; ++xi) dst[xi * 24] = f2bf(src[xi]);
  }
  // zero feats pad columns (seq 0 blocks cover all samples: 1024 x 16)
  if (seq == 0) {
    for (int i = tid; i < TBB * 16; i += 256)
      a.feats[(size_t)(b0 + i / 16) * FSTRIDE + 560 + (i % 16)] = 0;
  }
  __syncthreads();

  const int wave = tid >> 6, lane = tid & 63, quad = lane >> 4, m = lane & 15;

  // preload the 22 non-zero B fragments for this seq
  const bfrag* wp = a.Wpack + (size_t)(seq * 5 * 7) * 64 + lane;
  bfrag Bf[22];
  {
    int bi = 0;
#pragma unroll
    for (int i = 0; i < SN0; ++i) Bf[bi++] = wp[(0 * 7 + SLO0 + i) * 64];
#pragma unroll
    for (int i = 0; i < SN1; ++i) Bf[bi++] = wp[(1 * 7 + SLO1 + i) * 64];
#pragma unroll
    for (int i = 0; i < SN2; ++i) Bf[bi++] = wp[(2 * 7 + SLO2 + i) * 64];
#pragma unroll
    for (int i = 0; i < SN3; ++i) Bf[bi++] = wp[(3 * 7 + SLO3 + i) * 64];
#pragma unroll
    for (int i = 0; i < SN4; ++i) Bf[bi++] = wp[(4 * 7 + SLO4 + i) * 64];
  }
  // Bf base offsets per nt: {0, 1, 4, 9, 15}

  constexpr int njobs = (MTc == 2) ? TBB : ((TBB << SHIFTc) >> 4);
  constexpr int bpt = (MTc == 1 && SHIFTc == 3) ? 2 : 1;
  constexpr int lmask = (1 << SHIFTc) - 1;

  for (int job = wave; job < njobs; job += 4) {
    float v0 = 0.f, v1 = 0.f, v2 = 0.f, v3 = 0.f, v4 = 0.f;
#pragma unroll
    for (int sub = 0; sub < MTc; ++sub) {
      int bl, l;
      if (MTc == 2) { bl = job; l = sub * 2 + m; }          // dense overlapping tiles
      else { int r = job * 16 + m; bl = r >> SHIFTc; l = r & lmask; }
      const unsigned short* arow = &xl[(bl * P + l) * 24 + quad * 8];
      f32x4 acc0 = {0.f, 0.f, 0.f, 0.f}, acc1 = acc0, acc2 = acc0, acc3 = acc0, acc4 = acc0;
#pragma unroll
      for (int s = 0; s < 7; ++s) {
        bfrag Af = *(const bfrag*)(arow + s * 32);
        if (s >= SLO0 && s < SLO0 + SN0)
          acc0 = __builtin_amdgcn_mfma_f32_16x16x32_bf16(Af, Bf[0 + s - SLO0], acc0, 0, 0, 0);
        if (s >= SLO1 && s < SLO1 + SN1)
          acc1 = __builtin_amdgcn_mfma_f32_16x16x32_bf16(Af, Bf[1 + s - SLO1], acc1, 0, 0, 0);
        if (s >= SLO2 && s < SLO2 + SN2)
          acc2 = __builtin_amdgcn_mfma_f32_16x16x32_bf16(Af, Bf[4 + s - SLO2], acc2, 0, 0, 0);
        if (s >= SLO3 && s < SLO3 + SN3)
          acc3 = __builtin_amdgcn_mfma_f32_16x16x32_bf16(Af, Bf[9 + s - SLO3], acc3, 0, 0, 0);
        acc4 = __builtin_amdgcn_mfma_f32_16x16x32_bf16(Af, Bf[15 + s], acc4, 0, 0, 0);
      }
      // relu+max fold; mask only output rows l >= Lc (constant-folds where dense)
#pragma unroll
      for (int r4 = 0; r4 < 4; ++r4) {
        bool ok = (MTc == 2) ? true : (((quad * 4 + r4) & lmask) < Lc);
        v0 = fmaxf(v0, ok ? acc0[r4] : 0.f);
        v1 = fmaxf(v1, ok ? acc1[r4] : 0.f);
        v2 = fmaxf(v2, ok ? acc2[r4] : 0.f);
        v3 = fmaxf(v3, ok ? acc3[r4] : 0.f);
        v4 = fmaxf(v4, ok ? acc4[r4] : 0.f);
      }
    }
    v0 = fmaxf(v0, __shfl_xor(v0, 16));
    v1 = fmaxf(v1, __shfl_xor(v1, 16));
    v2 = fmaxf(v2, __shfl_xor(v2, 16));
    v3 = fmaxf(v3, __shfl_xor(v3, 16));
    v4 = fmaxf(v4, __shfl_xor(v4, 16));
    if (bpt == 1) {
      v0 = fmaxf(v0, __shfl_xor(v0, 32));
      v1 = fmaxf(v1, __shfl_xor(v1, 32));
      v2 = fmaxf(v2, __shfl_xor(v2, 32));
      v3 = fmaxf(v3, __shfl_xor(v3, 32));
      v4 = fmaxf(v4, __shfl_xor(v4, 32));
      if (lane < 16) {
        unsigned short* p = a.feats + (size_t)(b0 + job) * FSTRIDE + seq * 80 + lane;
        p[0] = f2bf(v0); p[16] = f2bf(v1); p[32] = f2bf(v2); p[48] = f2bf(v3); p[64] = f2bf(v4);
      }
    } else {
      // out rows 0-7 (quads 0,1) -> even sample ; rows 8-15 (quads 2,3) -> odd
      if ((lane & 16) == 0) {
        int b = b0 + job * 2 + (lane >> 5);
        unsigned short* p = a.feats + (size_t)b * FSTRIDE + seq * 80 + (lane & 15);
        p[0] = f2bf(v0); p[16] = f2bf(v1); p[32] = f2bf(v2); p[48] = f2bf(v3); p[64] = f2bf(v4);
      }
    }
  }
}

__global__ __launch_bounds__(256, 5) void conv_kernel(ConvArgs a) {
  __shared__ unsigned short xl[16 * 41 * 24];   // 31.5 KB -> 5 blocks/CU
  const int b0 = blockIdx.x * 16;
  switch (blockIdx.y) {
    case 0: conv_body<12, 4, 1>(xl, a, 0, b0); break;
    case 1: conv_body< 7, 3, 1>(xl, a, 1, b0); break;
    case 2: conv_body< 8, 3, 1>(xl, a, 2, b0); break;
    case 3: conv_body<16, 4, 1>(xl, a, 3, b0); break;
    case 4: conv_body< 6, 3, 1>(xl, a, 4, b0); break;
    case 5: conv_body< 7, 3, 1>(xl, a, 5, b0); break;
    default: conv_body<18, 5, 2>(xl, a, 6, b0); break;
  }
}

// ---------------- MLP: feats[B,560] -> sigmoid(@lin1^T+b1) -> @lin2^T+b2 ----------------
struct MlpArgs {
  const unsigned short* feats;
  const bfrag* lin1pack;
  const float* lin1_b;
  const float* lin2_w;
  const float* lin2_b;
  float* out;
};

__global__ __launch_bounds__(256) void mlp_kernel(MlpArgs a) {
  __shared__ float h[16 * 68];
  __shared__ float w2[64];
  const int tid = threadIdx.x;
  const int b0 = blockIdx.x * 16;
  if (tid < 64) w2[tid] = a.lin2_w[tid];
  const int wave = tid >> 6, lane = tid & 63, quad = lane >> 4, m = lane & 15;
  const int nt = wave;                     // one n-tile per wave
  const unsigned short* frow = a.feats + (size_t)(b0 + m) * FSTRIDE;
  f32x4 acc = {0.f, 0.f, 0.f, 0.f};
#pragma unroll
  for (int s = 0; s < 18; ++s) {
    bfrag af = *(const bfrag*)(frow + s * 32 + quad * 8);
    bfrag bf = a.lin1pack[(nt * 18 + s) * 64 + lane];
    acc = __builtin_amdgcn_mfma_f32_16x16x32_bf16(af, bf, acc, 0, 0, 0);
  }
  int n = nt * 16 + m;
  float bias = a.lin1_b[n];
#pragma unroll
  for (int r = 0; r < 4; ++r) {
    float pre = acc[r] + bias;
    h[(quad * 4 + r) * 68 + n] = 1.f / (1.f + __expf(-pre));
  }
  __syncthreads();
  int bl = tid >> 4, q = tid & 15;
  const float* hr = &h[bl * 68 + q * 4];
  float s = hr[0] * w2[q * 4] + hr[1] * w2[q * 4 + 1] + hr[2] * w2[q * 4 + 2] + hr[3] * w2[q * 4 + 3];
  s += __shfl_xor(s, 1);
  s += __shfl_xor(s, 2);
  s += __shfl_xor(s, 4);
  s += __shfl_xor(s, 8);
  if (q == 0) a.out[b0 + bl] = s + a.lin2_b[0];
}

// ---------------- launch ----------------
extern "C" void kernel_launch(void* const* d_in, const int* in_sizes, int n_in,
                              void* d_out, int out_size, void* d_ws, size_t ws_size,
                              hipStream_t stream) {
  (void)in_sizes; (void)n_in; (void)out_size; (void)ws_size;
  char* ws = (char*)d_ws;
  bfrag* Wpack = (bfrag*)(ws + 0);                 // 15680*16 = 250,880 B
  bfrag* lin1pack = (bfrag*)(ws + 262144);         // 4608*16  =  73,728 B
  unsigned short* feats = (unsigned short*)(ws + 393216);  // 16384*576*2 = 18.87 MB

  PrepArgs pa;
  for (int j = 0; j < 5; ++j) pa.Wk[j] = (const float*)d_in[7 + j];
  pa.lin1_w = (const float*)d_in[12];
  pa.Wpack = Wpack;
  pa.lin1pack = lin1pack;
  prep_kernel<<<80, 256, 0, stream>>>(pa);

  ConvArgs ca;
  for (int i = 0; i < NSEQ; ++i) ca.x[i] = (const float*)d_in[i];
  ca.Wpack = Wpack;
  ca.feats = feats;
  conv_kernel<<<dim3(16384 / 16, NSEQ), 256, 0, stream>>>(ca);

  MlpArgs ma;
  ma.feats = feats;
  ma.lin1pack = lin1pack;
  ma.lin1_b = (const float*)d_in[13];
  ma.lin2_w = (const float*)d_in[14];
  ma.lin2_b = (const float*)d_in[15];
  ma.out = (float*)d_out;
  mlp_kernel<<<16384 / 16, 256, 0, stream>>>(ma);
}

// Round 6
// 183.347 us; speedup vs baseline: 2.0000x; 2.0000x over previous
//
#include <hip/hip_runtime.h>
#include <stdint.h>
#include <stddef.h>

typedef short bfrag __attribute__((ext_vector_type(8)));
typedef float f32x4 __attribute__((ext_vector_type(4)));

#define NSEQ 7
// feats packed in MFMA A-fragment order: [btile(1024)][step(18)][lane(64)][j(8)] bf16
// value = feat[btile*16 + (lane&15)][k], k = step*32 + (lane>>4)*8 + j

__constant__ int c_ks[5] = {1, 3, 5, 7, 9};

// per-ksize active MFMA K-steps (B is exactly zero outside): s in [lo, lo+n)
#define SLO0 3
#define SLO1 2
#define SLO2 1
#define SLO3 0
#define SLO4 0
#define SN0 1
#define SN1 3
#define SN2 5
#define SN3 6
#define SN4 7

static __device__ __forceinline__ unsigned short f2bf(float f) {
  unsigned int u = __float_as_uint(f);
  u += 0x7FFFu + ((u >> 16) & 1u);   // RNE
  return (unsigned short)(u >> 16);
}

// ---------------- prep: pack conv weights + lin1 into B-fragment layout ----------
struct PrepArgs {
  const float* Wk[5];
  const float* lin1_w;
  bfrag* Wpack;
  bfrag* lin1pack;
};

__global__ __launch_bounds__(256) void prep_kernel(PrepArgs a) {
  int tid = blockIdx.x * 256 + threadIdx.x;
  const int NW = NSEQ * 5 * 7 * 64;
  if (tid < NW) {
    int lane = tid & 63, rest = tid >> 6;
    int step = rest % 7, nt = (rest / 7) % 5, seq = rest / 35;
    int quad = lane >> 4, f = lane & 15;
    int ks = c_ks[nt], off = (9 - ks) >> 1;
    const float* W = a.Wk[nt];
    bfrag s;
#pragma unroll
    for (int j = 0; j < 8; ++j) {
      int k = step * 32 + quad * 8 + j;
      int t = k / 24, c = k % 24;
      int tap = t - off;
      float val = 0.f;
      if (c < 20 && tap >= 0 && tap < ks)
        val = W[((seq * 16 + f) * 20 + c) * ks + tap] * 0.2f;  // fold /5
      s[j] = (short)f2bf(val);
    }
    a.Wpack[tid] = s;
  } else if (tid < NW + 4 * 18 * 64) {
    int t2 = tid - NW;
    int lane = t2 & 63, rest = t2 >> 6;
    int step = rest % 18, nt = rest / 18;
    int quad = lane >> 4, col = lane & 15;
    int n = nt * 16 + col;
    bfrag s;
#pragma unroll
    for (int j = 0; j < 8; ++j) {
      int k = step * 32 + quad * 8 + j;
      float val = (k < 560) ? a.lin1_w[n * 560 + k] : 0.f;  // zero rows k>=560 make feats pad inert
      s[j] = (short)f2bf(val);
    }
    a.lin1pack[t2] = s;
  }
}

// ---------------- conv+relu+gmax: im2col MFMA, one dispatch, per-seq constexpr ----------
struct ConvArgs {
  const float* x[NSEQ];
  const bfrag* Wpack;
  unsigned short* feats;   // packed A-frag layout, see top
};

static __device__ __forceinline__ void store_feat(unsigned short* feats, int b, int k, float v) {
  int step = k >> 5, q = (k >> 3) & 3, j = k & 7;
  feats[((size_t)(b >> 4) * 18 + step) * 512 + (q * 16 + (b & 15)) * 8 + j] = f2bf(v);
}

// MTc==1: Lp = 1<<SHIFTc <= 16. MTc==2: seq6 (L=18), two OVERLAPPING dense 16-row
// tiles per sample (rows 0-15 and 2-17; overlap idempotent under max).
template <int Lc, int SHIFTc, int MTc, int TBBv, int Pv>
__device__ __forceinline__ void conv_body(unsigned short* xl, const ConvArgs& a,
                                          const int seq, const int b0) {
  const int tid = threadIdx.x;
  const float* xg = a.x[seq];

  // zero staging region (covers c-pad, l-pad, halo) — vectorized
  for (int i = tid; i < TBBv * Pv * 24 / 8; i += 256) ((uint4*)xl)[i] = uint4{0, 0, 0, 0};
  __syncthreads();
  // stage x -> bf16 [b][pos=xi+4][c]
  for (int r = tid; r < TBBv * 20; r += 256) {
    int b = r / 20, c = r % 20;
    const float* src = xg + (size_t)((b0 + b) * 20 + c) * Lc;
    unsigned short* dst = xl + (b * Pv + 4) * 24 + c;
#pragma unroll
    for (int xi = 0; xi < Lc; ++xi) dst[xi * 24] = f2bf(src[xi]);
  }
  __syncthreads();

  const int wave = tid >> 6, lane = tid & 63, quad = lane >> 4, m = lane & 15;

  // preload the 22 non-zero B fragments for this seq
  const bfrag* wp = a.Wpack + (size_t)(seq * 5 * 7) * 64 + lane;
  bfrag Bf[22];
  {
    int bi = 0;
#pragma unroll
    for (int i = 0; i < SN0; ++i) Bf[bi++] = wp[(0 * 7 + SLO0 + i) * 64];
#pragma unroll
    for (int i = 0; i < SN1; ++i) Bf[bi++] = wp[(1 * 7 + SLO1 + i) * 64];
#pragma unroll
    for (int i = 0; i < SN2; ++i) Bf[bi++] = wp[(2 * 7 + SLO2 + i) * 64];
#pragma unroll
    for (int i = 0; i < SN3; ++i) Bf[bi++] = wp[(3 * 7 + SLO3 + i) * 64];
#pragma unroll
    for (int i = 0; i < SN4; ++i) Bf[bi++] = wp[(4 * 7 + SLO4 + i) * 64];
  }
  // Bf base offsets per nt: {0, 1, 4, 9, 15}

  constexpr int njobs = (MTc == 2) ? TBBv : ((TBBv << SHIFTc) >> 4);
  constexpr int bpt = (MTc == 1 && SHIFTc == 3) ? 2 : 1;
  constexpr int lmask = (1 << SHIFTc) - 1;

  for (int job = wave; job < njobs; job += 4) {
    float v0 = 0.f, v1 = 0.f, v2 = 0.f, v3 = 0.f, v4 = 0.f;
#pragma unroll
    for (int sub = 0; sub < MTc; ++sub) {
      int bl, l;
      if (MTc == 2) { bl = job; l = sub * 2 + m; }          // dense overlapping tiles
      else { int r = job * 16 + m; bl = r >> SHIFTc; l = r & lmask; }
      const unsigned short* arow = &xl[(bl * Pv + l) * 24 + quad * 8];
      f32x4 acc0 = {0.f, 0.f, 0.f, 0.f}, acc1 = acc0, acc2 = acc0, acc3 = acc0, acc4 = acc0;
#pragma unroll
      for (int s = 0; s < 7; ++s) {
        bfrag Af = *(const bfrag*)(arow + s * 32);
        if (s >= SLO0 && s < SLO0 + SN0)
          acc0 = __builtin_amdgcn_mfma_f32_16x16x32_bf16(Af, Bf[0 + s - SLO0], acc0, 0, 0, 0);
        if (s >= SLO1 && s < SLO1 + SN1)
          acc1 = __builtin_amdgcn_mfma_f32_16x16x32_bf16(Af, Bf[1 + s - SLO1], acc1, 0, 0, 0);
        if (s >= SLO2 && s < SLO2 + SN2)
          acc2 = __builtin_amdgcn_mfma_f32_16x16x32_bf16(Af, Bf[4 + s - SLO2], acc2, 0, 0, 0);
        if (s >= SLO3 && s < SLO3 + SN3)
          acc3 = __builtin_amdgcn_mfma_f32_16x16x32_bf16(Af, Bf[9 + s - SLO3], acc3, 0, 0, 0);
        acc4 = __builtin_amdgcn_mfma_f32_16x16x32_bf16(Af, Bf[15 + s], acc4, 0, 0, 0);
      }
      // relu+max fold; mask output rows l >= Lc (constant-folds where dense)
#pragma unroll
      for (int r4 = 0; r4 < 4; ++r4) {
        bool ok = (MTc == 2) ? true : (((quad * 4 + r4) & lmask) < Lc);
        v0 = fmaxf(v0, ok ? acc0[r4] : 0.f);
        v1 = fmaxf(v1, ok ? acc1[r4] : 0.f);
        v2 = fmaxf(v2, ok ? acc2[r4] : 0.f);
        v3 = fmaxf(v3, ok ? acc3[r4] : 0.f);
        v4 = fmaxf(v4, ok ? acc4[r4] : 0.f);
      }
    }
    v0 = fmaxf(v0, __shfl_xor(v0, 16));
    v1 = fmaxf(v1, __shfl_xor(v1, 16));
    v2 = fmaxf(v2, __shfl_xor(v2, 16));
    v3 = fmaxf(v3, __shfl_xor(v3, 16));
    v4 = fmaxf(v4, __shfl_xor(v4, 16));
    if (bpt == 1) {
      v0 = fmaxf(v0, __shfl_xor(v0, 32));
      v1 = fmaxf(v1, __shfl_xor(v1, 32));
      v2 = fmaxf(v2, __shfl_xor(v2, 32));
      v3 = fmaxf(v3, __shfl_xor(v3, 32));
      v4 = fmaxf(v4, __shfl_xor(v4, 32));
      if (lane < 16) {
        int b = b0 + job, kb = seq * 80 + lane;
        store_feat(a.feats, b, kb, v0);      store_feat(a.feats, b, kb + 16, v1);
        store_feat(a.feats, b, kb + 32, v2); store_feat(a.feats, b, kb + 48, v3);
        store_feat(a.feats, b, kb + 64, v4);
      }
    } else {
      // out rows 0-7 (quads 0,1) -> even sample ; rows 8-15 (quads 2,3) -> odd
      if ((lane & 16) == 0) {
        int b = b0 + job * 2 + (lane >> 5), kb = seq * 80 + (lane & 15);
        store_feat(a.feats, b, kb, v0);      store_feat(a.feats, b, kb + 16, v1);
        store_feat(a.feats, b, kb + 32, v2); store_feat(a.feats, b, kb + 48, v3);
        store_feat(a.feats, b, kb + 64, v4);
      }
    }
  }
}

__global__ __launch_bounds__(256, 3) void conv_kernel(ConvArgs a) {
  __shared__ __align__(16) unsigned short xl[32 * 25 * 24];   // 38.4 KB (seq6 uses 31.5 KB of it)
  const int bid = blockIdx.x;
  if (bid < 3072) {
    const int seq = bid >> 9, b0 = (bid & 511) * 32;
    switch (seq) {
      case 0: conv_body<12, 4, 1, 32, 25>(xl, a, 0, b0); break;
      case 1: conv_body< 7, 3, 1, 32, 25>(xl, a, 1, b0); break;
      case 2: conv_body< 8, 3, 1, 32, 25>(xl, a, 2, b0); break;
      case 3: conv_body<16, 4, 1, 32, 25>(xl, a, 3, b0); break;
      case 4: conv_body< 6, 3, 1, 32, 25>(xl, a, 4, b0); break;
      default: conv_body< 7, 3, 1, 32, 25>(xl, a, 5, b0); break;
    }
  } else {
    conv_body<18, 5, 2, 16, 41>(xl, a, 6, (bid - 3072) * 16);
  }
}

// ---------------- MLP: feats(packed)[B,560+pad] -> sigmoid(@lin1^T+b1) -> @lin2^T+b2 ----
struct MlpArgs {
  const bfrag* feats;      // packed A-frag layout
  const bfrag* lin1pack;
  const float* lin1_b;
  const float* lin2_w;
  const float* lin2_b;
  float* out;
};

__global__ __launch_bounds__(256, 4) void mlp_kernel(MlpArgs a) {
  __shared__ float h[32 * 68];
  __shared__ float w2[64];
  const int tid = threadIdx.x;
  const int b0 = blockIdx.x * 32, bt0 = b0 >> 4;
  if (tid < 64) w2[tid] = a.lin2_w[tid];
  const int wave = tid >> 6, lane = tid & 63, quad = lane >> 4, m = lane & 15;
  const int nt = wave;                     // one n-tile per wave
  // B fragments register-resident (18 x 4 VGPR = 72)
  bfrag Bf[18];
#pragma unroll
  for (int s = 0; s < 18; ++s) Bf[s] = a.lin1pack[(nt * 18 + s) * 64 + lane];
  int n = nt * 16 + m;
  float bias = a.lin1_b[n];
#pragma unroll
  for (int bt = 0; bt < 2; ++bt) {
    const bfrag* ap = a.feats + (size_t)(bt0 + bt) * 18 * 64 + lane;  // coalesced 16B/lane
    f32x4 acc = {0.f, 0.f, 0.f, 0.f};
#pragma unroll
    for (int s = 0; s < 18; ++s)
      acc = __builtin_amdgcn_mfma_f32_16x16x32_bf16(ap[s * 64], Bf[s], acc, 0, 0, 0);
#pragma unroll
    for (int r = 0; r < 4; ++r) {
      float pre = acc[r] + bias;
      h[(bt * 16 + quad * 4 + r) * 68 + n] = 1.f / (1.f + __expf(-pre));
    }
  }
  __syncthreads();
  int bl = tid >> 3, q = tid & 7;          // 8 threads per sample
  const float* hr = &h[bl * 68 + q * 8];
  float s = 0.f;
#pragma unroll
  for (int j = 0; j < 8; ++j) s += hr[j] * w2[q * 8 + j];
  s += __shfl_xor(s, 1);
  s += __shfl_xor(s, 2);
  s += __shfl_xor(s, 4);
  if (q == 0) a.out[b0 + bl] = s + a.lin2_b[0];
}

// ---------------- launch ----------------
extern "C" void kernel_launch(void* const* d_in, const int* in_sizes, int n_in,
                              void* d_out, int out_size, void* d_ws, size_t ws_size,
                              hipStream_t stream) {
  (void)in_sizes; (void)n_in; (void)out_size; (void)ws_size;
  char* ws = (char*)d_ws;
  bfrag* Wpack = (bfrag*)(ws + 0);                 // 15680*16 = 250,880 B
  bfrag* lin1pack = (bfrag*)(ws + 262144);         // 4608*16  =  73,728 B
  unsigned short* feats = (unsigned short*)(ws + 393216);  // 1024*18*64*16 = 18.87 MB

  PrepArgs pa;
  for (int j = 0; j < 5; ++j) pa.Wk[j] = (const float*)d_in[7 + j];
  pa.lin1_w = (const float*)d_in[12];
  pa.Wpack = Wpack;
  pa.lin1pack = lin1pack;
  prep_kernel<<<80, 256, 0, stream>>>(pa);

  ConvArgs ca;
  for (int i = 0; i < NSEQ; ++i) ca.x[i] = (const float*)d_in[i];
  ca.Wpack = Wpack;
  ca.feats = feats;
  // 3072 blocks: seqs 0-5 (TBB=32) ; 1024 blocks: seq 6 (TBB=16)
  conv_kernel<<<4096, 256, 0, stream>>>(ca);

  MlpArgs ma;
  ma.feats = (const bfrag*)feats;
  ma.lin1pack = lin1pack;
  ma.lin1_b = (const float*)d_in[13];
  ma.lin2_w = (const float*)d_in[14];
  ma.lin2_b = (const float*)d_in[15];
  ma.out = (float*)d_out;
  mlp_kernel<<<16384 / 32, 256, 0, stream>>>(ma);
}